// Round 1
// 719.374 us; speedup vs baseline: 1.1376x; 1.1376x over previous
//
#include <hip/hip_runtime.h>

typedef __bf16 bf16x8 __attribute__((ext_vector_type(8)));
typedef float floatx4 __attribute__((ext_vector_type(4)));

__device__ __forceinline__ float sigmoidf_(float v) {
    return 1.0f / (1.0f + __expf(-v));
}

// 512 threads/block, 2 blocks/CU (VGPR<=128 via launch_bounds, LDS 71808B).
// smem layout (floats):
// [0,2112)      rowsum [64][33]   (A..B)  | G [0,4096) (C..E)
// [2112,4224)   colsum [64][33]   (A..B)
// [4096,8192)   T1 (C-dump..E)    | astage [4224,8320) (A only, tail overlaps sh)
// [8192,10240)  sh [64][32] (B..C) | stats scratch (D)
// [10240,12288) sw [64][32] (B..C)
// [12288,16512) ring: 4 slots x 66 x 32 bf16 (C) | sg[4096] f32 (E)
// [16512,17568) zrow: 66x32 bf16, zero
// [17568,17952) misc
extern "C" __global__ __launch_bounds__(512, 4)
void ema_fused(const float* __restrict__ x, const float* __restrict__ w1,
               const float* __restrict__ b1, const float* __restrict__ w3,
               const float* __restrict__ b3, const float* __restrict__ gamma,
               const float* __restrict__ beta, float* __restrict__ out)
{
    __shared__ float sm[17952];
    const int t = threadIdx.x;
    const int b = blockIdx.x;
    const float* gx = x + (size_t)b * 131072;
    float* gout = out + (size_t)b * 131072;

    const int c = t & 31;        // channel owned (phases A/C)
    const int k = t >> 5;        // w-group 0..15
    const int lane = t & 63;
    const int wave = t >> 6;     // 0..7
    const int nf = wave & 1;     // which 16-col half of conv output
    const int wbase = (wave >> 1) * 16;
    const int m_ = lane & 15;
    const int q_ = lane >> 4;

    float* rowsum = sm;              // stride 33 (bank-conflict-free reads)
    float* colsum = sm + 2112;       // stride 33
    float* G      = sm;
    float* T1     = sm + 4096;
    float* astage = sm + 4224;       // [8][16][32]
    float* shl    = sm + 8192;
    float* swl    = sm + 10240;
    __bf16* ringbase = (__bf16*)(sm + 12288);   // slot s at +s*2112 (bf16 elems)
    float*  sgbuf    = sm + 12288;              // reuse ring after h-loop
    __bf16* zrow     = (__bf16*)(sm + 16512);
    float* x21    = sm + 17568;
    float* x11    = sm + 17600;
    float* a1v    = sm + 17632;
    float* a0v    = sm + 17664;
    float* b3c    = sm + 17696;
    float* corners= sm + 17728;  // [4][32]
    float* Stot   = sm + 17856;
    float* meanx2 = sm + 17888;

    // ---------------- Phase A: rowsum / colsum / corners ----------------
    float colacc[4];
#pragma unroll
    for (int i = 0; i < 4; ++i) colacc[i] = 0.f;

    for (int h8 = 0; h8 < 8; ++h8) {
#pragma unroll
        for (int j = 0; j < 8; ++j) {
            int h = h8 * 8 + j;
            float part = 0.f;
#pragma unroll
            for (int i = 0; i < 4; ++i) {
                int w = k + 16 * i;
                float v = gx[(h * 64 + w) * 32 + c];
                colacc[i] += v;
                part += v;
                if ((h == 0 || h == 63) && w == 0)
                    corners[((h == 63) ? 2 : 0) * 32 + c] = v;
                if ((h == 0 || h == 63) && w == 63)
                    corners[((h == 63) ? 3 : 1) * 32 + c] = v;
            }
            astage[(j * 16 + k) * 32 + c] = part;
        }
        __syncthreads();
        if (t < 256) {
            int j2 = t >> 5, c2 = t & 31;
            float s = 0.f;
#pragma unroll
            for (int k2 = 0; k2 < 16; ++k2) s += astage[(j2 * 16 + k2) * 32 + c2];
            rowsum[(h8 * 8 + j2) * 33 + c2] = s;
        }
        __syncthreads();
    }
#pragma unroll
    for (int i = 0; i < 4; ++i) colsum[(k + 16 * i) * 33 + c] = colacc[i];
    __syncthreads();

    // ---------------- Phase B: sh, sw, mean_x2 (analytic), x21, x11 ----------------
    {
        const int hh = t >> 3;          // 0..63
        const int d0 = (t & 7) * 4;
        float acch[4], accw[4];
#pragma unroll
        for (int kk = 0; kk < 4; ++kk) { acch[kk] = b1[d0 + kk]; accw[kk] = b1[d0 + kk]; }
        for (int ci = 0; ci < 32; ++ci) {
            float rs = rowsum[hh * 33 + ci] * (1.f / 64.f);
            float cs = colsum[hh * 33 + ci] * (1.f / 64.f);
#pragma unroll
            for (int kk = 0; kk < 4; ++kk) {
                float wv = w1[ci * 32 + d0 + kk];
                acch[kk] += rs * wv;
                accw[kk] += cs * wv;
            }
        }
#pragma unroll
        for (int kk = 0; kk < 4; ++kk) {
            shl[hh * 32 + d0 + kk] = sigmoidf_(acch[kk]);
            swl[hh * 32 + d0 + kk] = sigmoidf_(accw[kk]);
        }
    }
    if (t < 32) {
        float s = 0.f;
        for (int h = 0; h < 64; ++h) s += rowsum[h * 33 + t];
        Stot[t] = s;
        b3c[t] = b3[t];
    }
    __syncthreads();
    if (t < 32) {   // mean of conv output per co, from window sums
        int co = t;
        float acc = 0.f;
        for (int dh = -1; dh <= 1; ++dh)
            for (int dw = -1; dw <= 1; ++dw) {
                int ks = (dh + 1) * 3 + (dw + 1);
                for (int ci = 0; ci < 32; ++ci) {
                    float S = Stot[ci];
                    if (dh == -1) S -= rowsum[63 * 33 + ci];
                    if (dh ==  1) S -= rowsum[ci];
                    if (dw == -1) S -= colsum[63 * 33 + ci];
                    if (dw ==  1) S -= colsum[ci];
                    if (dh == -1 && dw == -1) S += corners[3 * 32 + ci];
                    if (dh == -1 && dw ==  1) S += corners[2 * 32 + ci];
                    if (dh ==  1 && dw == -1) S += corners[1 * 32 + ci];
                    if (dh ==  1 && dw ==  1) S += corners[0 * 32 + ci];
                    acc += w3[ks * 1024 + ci * 32 + co] * S;
                }
            }
        meanx2[co] = acc * (1.f / 4096.f) + b3[co];
    }
    __syncthreads();
    if (t == 0) {   // x21 = softmax(mean_x2)
        float m = meanx2[0];
        for (int i = 1; i < 32; ++i) m = fmaxf(m, meanx2[i]);
        float s = 0.f;
        for (int i = 0; i < 32; ++i) { float e = __expf(meanx2[i] - m); x21[i] = e; s += e; }
        float inv = 1.f / s;
        for (int i = 0; i < 32; ++i) x21[i] *= inv;
    } else if (t == 64) {   // x11 = softmax(beta)
        float m = -1e30f;
        for (int i = 0; i < 32; ++i) m = fmaxf(m, beta[i]);
        float s = 0.f;
        for (int i = 0; i < 32; ++i) s += __expf(beta[i] - m);
        float inv = 1.f / s;
        for (int i = 0; i < 32; ++i) x11[i] = __expf(beta[i] - m) * inv;
    }
    __syncthreads();

    // ---------------- B-fragments for conv (one nf-half per wave) ----------------
    bf16x8 Bf[9];
    {
        int ci0 = (lane >> 4) * 8;
        int co  = (lane & 15) + nf * 16;
#pragma unroll
        for (int ks = 0; ks < 9; ++ks) {
            bf16x8 v;
#pragma unroll
            for (int j = 0; j < 8; ++j)
                v[j] = (__bf16)w3[ks * 1024 + (ci0 + j) * 32 + co];
            Bf[ks] = v;
        }
    }

    // ---------------- Phase C init: zero G, zrow, ring halos ----------------
    for (int i = t; i < 4096; i += 512) G[i] = 0.f;
    for (int i = t; i < 1056; i += 512) sm[16512 + i] = 0.f;  // zrow
    if (t < 256) {
        int s = t >> 6, colsel = (t >> 5) & 1, cc = t & 31;
        ringbase[s * 2112 + (colsel ? 65 * 32 : 0) + cc] = (__bf16)0.f;
    }
    __syncthreads();

    // ---------------- Phase C: pipelined stream; gated+G+stats and MFMA conv ----------------
    float sumg = 0.f, sumg2 = 0.f;
    float T1a0[4] = {0.f, 0.f, 0.f, 0.f};
    float T1a1[4] = {0.f, 0.f, 0.f, 0.f};
    float pre[4];

    auto issue = [&](int r) {      // global loads only (hide under MFMA phase)
#pragma unroll
        for (int i = 0; i < 4; ++i)
            pre[i] = gx[(r * 64 + k + 16 * i) * 32 + c];
    };
    auto commit = [&](int r) {     // consume pre: ring write + gated + G
        __bf16* rowp = ringbase + (r & 3) * 2112;
        float coef = x21[r >> 1];
        int par = (r & 1) << 11;
        float sr = shl[r * 32 + c];
#pragma unroll
        for (int i = 0; i < 4; ++i) {
            int w = k + 16 * i;
            float v = pre[i];
            rowp[(w + 1) * 32 + c] = (__bf16)v;
            float g = v * sr * swl[w * 32 + c];
            sumg += g; sumg2 += g * g;
            G[par + w * 32 + c] += coef * g;
        }
    };
    auto conv_row = [&](int h) -> floatx4 {
        floatx4 acc = {0.f, 0.f, 0.f, 0.f};
#pragma unroll
        for (int dh = -1; dh <= 1; ++dh) {
            int r = h + dh;
            const __bf16* rowp = (r < 0 || r > 63) ? zrow : (ringbase + (r & 3) * 2112);
#pragma unroll
            for (int dw = -1; dw <= 1; ++dw) {
                int ks = (dh + 1) * 3 + (dw + 1);
                const __bf16* ap = rowp + (wbase + m_ + dw + 1) * 32 + q_ * 8;
                bf16x8 av = *(const bf16x8*)ap;
                acc = __builtin_amdgcn_mfma_f32_16x16x32_bf16(av, Bf[ks], acc, 0, 0, 0);
            }
        }
        return acc;
    };

    issue(0); commit(0); issue(1);
    for (int h2 = 0; h2 < 32; ++h2) {
        {   // even row
            const int h = 2 * h2;
            commit(h + 1);                 // loads issued one iteration ago
            if (h < 62) issue(h + 2);
            __syncthreads();
            floatx4 acc = conv_row(h);
            float coef = x11[h2];
#pragma unroll
            for (int rr = 0; rr < 4; ++rr) T1a0[rr] += coef * acc[rr];
        }
        {   // odd row
            const int h = 2 * h2 + 1;
            if (h < 63) commit(h + 1);
            if (h < 62) issue(h + 2);
            __syncthreads();
            floatx4 acc = conv_row(h);
            float coef = x11[h2];
#pragma unroll
            for (int rr = 0; rr < 4; ++rr) T1a1[rr] += coef * acc[rr];
        }
    }

    // ---------------- T1 dump (regs -> LDS) + stats scratch ----------------
    {
        const int colw = m_ + nf * 16;
#pragma unroll
        for (int rr = 0; rr < 4; ++rr) {
            int w = wbase + q_ * 4 + rr;
            T1[w * 32 + colw]        = T1a0[rr];
            T1[2048 + w * 32 + colw] = T1a1[rr];
        }
    }
    shl[k * 32 + c] = sumg;          // sh area reused as scratch (dead now)
    shl[512 + k * 32 + c] = sumg2;
    __syncthreads();

    // ---------------- Phase D: group stats -> a1, a0 ----------------
    if (t < 32) {
        float S = 0.f, S2 = 0.f;
#pragma unroll
        for (int kk = 0; kk < 16; ++kk) { S += shl[kk * 32 + t]; S2 += shl[512 + kk * 32 + t]; }
        float mu  = S * (1.f / 4096.f);
        float var = S2 * (1.f / 4096.f) - mu * mu;
        float rs  = rsqrtf(var + 0.001f);
        float g1  = gamma[t] * rs;
        a1v[t] = g1;
        a0v[t] = beta[t] - g1 * mu;
    }
    __syncthreads();

    // ---------------- Phase E0: sigmoid(weights) once per spatial pos ----------------
#pragma unroll 2
    for (int idx = t; idx < 4096; idx += 512) {
        int cp = idx & 31;
        float wt = T1[idx] + b3c[cp] + a1v[cp] * G[idx] + a0v[cp];
        sgbuf[idx] = sigmoidf_(wt);
    }
    __syncthreads();

    // ---------------- Phase E: out = gx * sg  (float4 stream) ----------------
    {
        const floatx4* gx4 = (const floatx4*)gx;
        floatx4* gout4 = (floatx4*)gout;
#pragma unroll 4
        for (int j = 0; j < 64; ++j) {
            int idx4 = t + 512 * j;
            float s = sgbuf[idx4 >> 3];
            floatx4 v = gx4[idx4];
            v[0] *= s; v[1] *= s; v[2] *= s; v[3] *= s;
            gout4[idx4] = v;
        }
    }
}

extern "C" void kernel_launch(void* const* d_in, const int* in_sizes, int n_in,
                              void* d_out, int out_size, void* d_ws, size_t ws_size,
                              hipStream_t stream) {
    const float* x  = (const float*)d_in[0];
    const float* w1 = (const float*)d_in[1];
    const float* b1 = (const float*)d_in[2];
    const float* w3 = (const float*)d_in[3];
    const float* b3 = (const float*)d_in[4];
    const float* gg = (const float*)d_in[5];
    const float* gb = (const float*)d_in[6];
    float* out = (float*)d_out;
    hipLaunchKernelGGL(ema_fused, dim3(512), dim3(512), 0, stream,
                       x, w1, b1, w3, b3, gg, gb, out);
}

// Round 3
// 606.823 us; speedup vs baseline: 1.3486x; 1.1855x over previous
//
#include <hip/hip_runtime.h>

typedef __bf16 bf16x8 __attribute__((ext_vector_type(8)));
typedef __bf16 bf16x4 __attribute__((ext_vector_type(4)));
typedef float floatx4 __attribute__((ext_vector_type(4)));

__device__ __forceinline__ float sigmoidf_(float v) {
    return 1.0f / (1.0f + __expf(-v));
}

// 512 threads/block, 2 blocks/CU. LDS = 19616 floats = 78464 B (2x <= 160KB/CU).
// layout (floats):
// [0,4224)      rowsum[64][33] + colsum[64][33] (A..B) | G [2][64][36]=4608 (C..E)
// [4608,8704)   T1 [2][64][32] (C-dump..E) | astage [8][8][32]=2048 (A only)
// [8704,10816)  shl[64][33] (B..C) | sumg scratch (D)
// [10816,12928) swl[64][33] (B..C) | sumg2 scratch (D)
// [12928,19264) ring: 6 slots x 66 rows x 64B bf16, XOR-swizzled | sgbuf[4096] (E)
// [19264,19616) misc
extern "C" __global__ __launch_bounds__(512, 4)
void ema_fused(const float* __restrict__ x, const float* __restrict__ w1,
               const float* __restrict__ b1, const float* __restrict__ w3,
               const float* __restrict__ b3, const float* __restrict__ gamma,
               const float* __restrict__ beta, float* __restrict__ out)
{
    __shared__ float sm[19616];
    const int t = threadIdx.x;
    const int b = blockIdx.x;
    const float* gx = x + (size_t)b * 131072;
    float* gout = out + (size_t)b * 131072;
    const floatx4* gx4 = (const floatx4*)gx;

    const int wA = t >> 3;          // spatial w owned (A/C commit/E0): 0..63
    const int c0 = (t & 7) * 4;     // first of 4 channels owned
    const int lane = t & 63;
    const int wave = t >> 6;        // 0..7
    const int nf = wave & 1;        // conv output half
    const int wbase = (wave >> 1) * 16;
    const int m_ = lane & 15;
    const int q_ = lane >> 4;

    float* rowsum = sm;              // [64][33]
    float* colsum = sm + 2112;       // [64][33]
    float* G      = sm;              // [2][64][36]
    float* T1     = sm + 4608;       // [2][64][32]
    float* astage = sm + 4608;       // [8][8][32] (A only, 2048 floats)
    float* shl    = sm + 8704;       // [64][33]
    float* swl    = sm + 10816;      // [64][33]
    __bf16* ringbase = (__bf16*)(sm + 12928);   // 6 slots x 2112 bf16
    float*  sgbuf    = sm + 12928;              // reuse ring in E
    float* x21    = sm + 19264;
    float* x11    = sm + 19296;
    float* a1v    = sm + 19328;
    float* a0v    = sm + 19360;
    float* b3c    = sm + 19392;
    float* corners= sm + 19424;  // [4][32]
    float* Stot   = sm + 19552;
    float* meanx2 = sm + 19584;

    // ---------------- Phase A: rowsum / colsum / corners (float4 + wave reduce) ----------------
    floatx4 colacc4 = {0.f, 0.f, 0.f, 0.f};
    for (int h8 = 0; h8 < 8; ++h8) {
        floatx4 rv[8];
#pragma unroll
        for (int j = 0; j < 8; ++j) rv[j] = gx4[(h8 * 8 + j) * 512 + t];
#pragma unroll
        for (int j = 0; j < 8; ++j) colacc4 += rv[j];
        if (h8 == 0 && (wA == 0 || wA == 63)) {
            int ci = (wA == 63) ? 1 : 0;
#pragma unroll
            for (int i2 = 0; i2 < 4; ++i2) corners[ci * 32 + c0 + i2] = rv[0][i2];
        }
        if (h8 == 7 && (wA == 0 || wA == 63)) {
            int ci = (wA == 63) ? 3 : 2;
#pragma unroll
            for (int i2 = 0; i2 < 4; ++i2) corners[ci * 32 + c0 + i2] = rv[7][i2];
        }
        // intra-wave reduce over the wave's 8 w-positions (lane bits 3,4,5)
#pragma unroll
        for (int j = 0; j < 8; ++j) {
            floatx4 s = rv[j];
#pragma unroll
            for (int i2 = 0; i2 < 4; ++i2) {
                float v = s[i2];
                v += __shfl_xor(v, 8);
                v += __shfl_xor(v, 16);
                v += __shfl_xor(v, 32);
                s[i2] = v;
            }
            if (lane < 8)
                *(floatx4*)&astage[(j * 8 + wave) * 32 + lane * 4] = s;
        }
        __syncthreads();
        if (t < 256) {   // final reduce over 8 waves
            int j2 = t >> 5, c2 = t & 31;
            float s = 0.f;
#pragma unroll
            for (int wv = 0; wv < 8; ++wv) s += astage[(j2 * 8 + wv) * 32 + c2];
            rowsum[(h8 * 8 + j2) * 33 + c2] = s;
        }
        __syncthreads();
    }
#pragma unroll
    for (int i = 0; i < 4; ++i) colsum[wA * 33 + c0 + i] = colacc4[i];
    __syncthreads();

    // ---------------- Phase B: sh, sw, mean_x2 (analytic), x21, x11 ----------------
    {
        const int hh = t >> 3;          // 0..63
        const int d0 = (t & 7) * 4;
        float acch[4], accw[4];
#pragma unroll
        for (int kk = 0; kk < 4; ++kk) { acch[kk] = b1[d0 + kk]; accw[kk] = b1[d0 + kk]; }
        for (int ci = 0; ci < 32; ++ci) {
            float rs = rowsum[hh * 33 + ci] * (1.f / 64.f);
            float cs = colsum[hh * 33 + ci] * (1.f / 64.f);
#pragma unroll
            for (int kk = 0; kk < 4; ++kk) {
                float wv = w1[ci * 32 + d0 + kk];
                acch[kk] += rs * wv;
                accw[kk] += cs * wv;
            }
        }
#pragma unroll
        for (int kk = 0; kk < 4; ++kk) {
            shl[hh * 33 + d0 + kk] = sigmoidf_(acch[kk]);
            swl[hh * 33 + d0 + kk] = sigmoidf_(accw[kk]);
        }
    }
    if (t < 32) {
        float s = 0.f;
        for (int h = 0; h < 64; ++h) s += rowsum[h * 33 + t];
        Stot[t] = s;
        b3c[t] = b3[t];
    }
    __syncthreads();
    if (t < 32) {   // mean of conv output per co, from window sums
        int co = t;
        float acc = 0.f;
        for (int dh = -1; dh <= 1; ++dh)
            for (int dw = -1; dw <= 1; ++dw) {
                int ks = (dh + 1) * 3 + (dw + 1);
                for (int ci = 0; ci < 32; ++ci) {
                    float S = Stot[ci];
                    if (dh == -1) S -= rowsum[63 * 33 + ci];
                    if (dh ==  1) S -= rowsum[ci];
                    if (dw == -1) S -= colsum[63 * 33 + ci];
                    if (dw ==  1) S -= colsum[ci];
                    if (dh == -1 && dw == -1) S += corners[3 * 32 + ci];
                    if (dh == -1 && dw ==  1) S += corners[2 * 32 + ci];
                    if (dh ==  1 && dw == -1) S += corners[1 * 32 + ci];
                    if (dh ==  1 && dw ==  1) S += corners[0 * 32 + ci];
                    acc += w3[ks * 1024 + ci * 32 + co] * S;
                }
            }
        meanx2[co] = acc * (1.f / 4096.f) + b3[co];
    }
    __syncthreads();
    if (t == 0) {   // x21 = softmax(mean_x2)
        float m = meanx2[0];
        for (int i = 1; i < 32; ++i) m = fmaxf(m, meanx2[i]);
        float s = 0.f;
        for (int i = 0; i < 32; ++i) { float e = __expf(meanx2[i] - m); x21[i] = e; s += e; }
        float inv = 1.f / s;
        for (int i = 0; i < 32; ++i) x21[i] *= inv;
    } else if (t == 64) {   // x11 = softmax(beta)
        float m = -1e30f;
        for (int i = 0; i < 32; ++i) m = fmaxf(m, beta[i]);
        float s = 0.f;
        for (int i = 0; i < 32; ++i) s += __expf(beta[i] - m);
        float inv = 1.f / s;
        for (int i = 0; i < 32; ++i) x11[i] = __expf(beta[i] - m) * inv;
    }
    __syncthreads();

    // per-thread constants for phase C
    floatx4 swv;
#pragma unroll
    for (int i = 0; i < 4; ++i) swv[i] = swl[wA * 33 + c0 + i];
    const int swzW = (((wA + 1) >> 1) & 3) << 4;           // write swizzle for row W=wA+1
    const int wrOff = (wA + 1) * 64 + ((c0 * 2) ^ swzW);   // byte offset within slot
    int rdOff[3];
#pragma unroll
    for (int dwi = 0; dwi < 3; ++dwi) {
        int W = wbase + m_ + dwi;                           // dw = dwi-1, +1 halo
        rdOff[dwi] = W * 64 + ((q_ * 16) ^ ((((W >> 1) & 3)) << 4));
    }

    // ---------------- B-fragments for conv ----------------
    bf16x8 Bf[9];
    {
        int ci0 = q_ * 8;
        int co  = m_ + nf * 16;
#pragma unroll
        for (int ks = 0; ks < 9; ++ks) {
            bf16x8 v;
#pragma unroll
            for (int j = 0; j < 8; ++j)
                v[j] = (__bf16)w3[ks * 1024 + (ci0 + j) * 32 + co];
            Bf[ks] = v;
        }
    }

    // ---------------- Phase C init: zero G, ring halo rows ----------------
    for (int i = t; i < 4608; i += 512) G[i] = 0.f;
    if (t < 192) {   // 6 slots x 2 halo rows (W=0,65) x 16 floats
        int s = t >> 5, which = (t >> 4) & 1, i16 = t & 15;
        ((float*)ringbase)[s * 1056 + (which ? 65 * 16 : 0) + i16] = 0.f;
    }
    __syncthreads();

    // ---------------- Phase C: 2 rows/barrier, depth-2 prefetch ----------------
    floatx4 sumg4 = {0.f,0.f,0.f,0.f}, sumg24 = {0.f,0.f,0.f,0.f};
    float T1a0[4] = {0.f,0.f,0.f,0.f};
    float T1a1[4] = {0.f,0.f,0.f,0.f};

    auto loadrow = [&](int r) -> floatx4 { return gx4[r * 512 + t]; };

    auto commit = [&](int r, floatx4 v) {
        int slot = r % 6;
        float coef = x21[r >> 1];
        floatx4 g;
#pragma unroll
        for (int i = 0; i < 4; ++i)
            g[i] = v[i] * shl[r * 33 + c0 + i] * swv[i];
        sumg4 += g;
        sumg24 += g * g;
        bf16x4 pk;
#pragma unroll
        for (int i = 0; i < 4; ++i) pk[i] = (__bf16)v[i];
        *(bf16x4*)((char*)ringbase + slot * 4224 + wrOff) = pk;
        int par = (r & 1) * 2304;
        floatx4* gp = (floatx4*)&G[par + wA * 36 + c0];
        *gp += coef * g;
    };

    auto conv_row = [&](int h, float* T1a) {
        floatx4 acc = {0.f, 0.f, 0.f, 0.f};
#pragma unroll
        for (int dh = -1; dh <= 1; ++dh) {
            int r = h + dh;
            if (r < 0 || r > 63) continue;
            const char* slotp = (const char*)ringbase + (r % 6) * 4224;
#pragma unroll
            for (int dwi = 0; dwi < 3; ++dwi) {
                bf16x8 av = *(const bf16x8*)(slotp + rdOff[dwi]);
                acc = __builtin_amdgcn_mfma_f32_16x16x32_bf16(av, Bf[(dh + 1) * 3 + dwi], acc, 0, 0, 0);
            }
        }
        float coef = x11[h >> 1];
#pragma unroll
        for (int rr = 0; rr < 4; ++rr) T1a[rr] += coef * acc[rr];
    };

    floatx4 pB0, pB1, pA0, pA1;
    pB0 = loadrow(0);
    commit(0, pB0);
    pB0 = loadrow(1); pB1 = loadrow(2);
    pA0 = loadrow(3); pA1 = loadrow(4);

    for (int h = 0; h < 64; h += 2) {
        commit(h + 1, pB0);
        if (h + 2 < 64) commit(h + 2, pB1);
        pB0 = pA0; pB1 = pA1;
        if (h + 5 < 64) pA0 = loadrow(h + 5);
        if (h + 6 < 64) pA1 = loadrow(h + 6);
        __syncthreads();
        conv_row(h, T1a0);
        conv_row(h + 1, T1a1);
    }

    // ---------------- T1 dump (regs -> LDS) + stats scratch ----------------
    {
        const int colw = m_ + nf * 16;
#pragma unroll
        for (int rr = 0; rr < 4; ++rr) {
            int w = wbase + q_ * 4 + rr;
            T1[w * 32 + colw]        = T1a0[rr];
            T1[2048 + w * 32 + colw] = T1a1[rr];
        }
    }
#pragma unroll
    for (int i = 0; i < 4; ++i) {
        shl[wA * 33 + c0 + i] = sumg4[i];     // shl/swl dead -> scratch
        swl[wA * 33 + c0 + i] = sumg24[i];
    }
    __syncthreads();

    // ---------------- Phase D: group stats -> a1, a0 ----------------
    if (t < 32) {
        float S = 0.f, S2 = 0.f;
        for (int w2 = 0; w2 < 64; ++w2) { S += shl[w2 * 33 + t]; S2 += swl[w2 * 33 + t]; }
        float mu  = S * (1.f / 4096.f);
        float var = S2 * (1.f / 4096.f) - mu * mu;
        float rs  = rsqrtf(var + 0.001f);
        float g1  = gamma[t] * rs;
        a1v[t] = g1;
        a0v[t] = beta[t] - g1 * mu;
    }
    __syncthreads();

    // ---------------- Phase E0: sigmoid(weights) once per position ----------------
#pragma unroll 2
    for (int idx = t; idx < 4096; idx += 512) {
        int cp = idx & 31;
        int wv2 = (idx >> 5) & 63;
        int par = (idx >> 11) * 2304;
        float wt = T1[idx] + b3c[cp] + a1v[cp] * G[par + wv2 * 36 + cp] + a0v[cp];
        sgbuf[idx] = sigmoidf_(wt);
    }
    __syncthreads();

    // ---------------- Phase E: out = gx * sg  (float4 stream) ----------------
    {
        floatx4* gout4 = (floatx4*)gout;
#pragma unroll 4
        for (int j = 0; j < 64; ++j) {
            int idx4 = t + 512 * j;
            float s = sgbuf[idx4 >> 3];
            floatx4 v = gx4[idx4];
            v[0] *= s; v[1] *= s; v[2] *= s; v[3] *= s;
            gout4[idx4] = v;
        }
    }
}

extern "C" void kernel_launch(void* const* d_in, const int* in_sizes, int n_in,
                              void* d_out, int out_size, void* d_ws, size_t ws_size,
                              hipStream_t stream) {
    const float* x  = (const float*)d_in[0];
    const float* w1 = (const float*)d_in[1];
    const float* b1 = (const float*)d_in[2];
    const float* w3 = (const float*)d_in[3];
    const float* b3 = (const float*)d_in[4];
    const float* gg = (const float*)d_in[5];
    const float* gb = (const float*)d_in[6];
    float* out = (float*)d_out;
    hipLaunchKernelGGL(ema_fused, dim3(512), dim3(512), 0, stream,
                       x, w1, b1, w3, b3, gg, gb, out);
}